// Round 1
// baseline (431.078 us; speedup 1.0000x reference)
//
#include <hip/hip_runtime.h>

// S_GC_att_A round 5: kill the Xs staging + halve the barriers.
// R4 post-mortem: 203us, MfmaUtil 24.6% == pure-MFMA time exactly -> still
// stall-bound. 60 barriers/block; staging = 22.5K scalar ds_write_u16/block
// (the bulk of 11.6M bank conflicts) + div-by-22 VALU + 114KB/chunk of ax
// LDS re-reads -- all for data each wave consumes ALONE.
// R5: (a) ax fragments loaded DIRECTLY global->reg per chunk (tv-linear is
// legal: Ms rows v>=22 are zero, so kk=22..31 of A multiply 0; float2 loads
// clamped to kk<=20 -> never OOB). Xs deleted (-13.3KB LDS, -1 barrier/chunk).
// (b) Zs double-buffered -> ONE barrier per k (28 total): z(k+1) writes the
// other buffer while laggards finish main(k). (c) setprio(1) around main MFMA
// cluster -- waves now sit in different phases, scheduler has a choice.
// LDS 36512B -> still 4 blocks/CU. Watch VGPR: ax +16 live (target <=128 incl AGPR).

#define TT    4
#define NTW   88     // TT*22
#define CHUNK 64
#define MROWS 176    // 7*24 + 8 pad rows
#define WB_BYTES (7 * 256 * 256 * 2)

typedef __attribute__((ext_vector_type(8))) __bf16    bf16x8;
typedef __attribute__((ext_vector_type(4))) float     f32x4;
typedef __attribute__((ext_vector_type(8))) short     s16x8;
typedef __attribute__((ext_vector_type(2))) unsigned  u32x2;
typedef __attribute__((ext_vector_type(4))) unsigned  u32x4;

__device__ __forceinline__ unsigned short f2bf_rn(float f) {  // RNE
  union { float f; unsigned u; } x; x.f = f;
  return (unsigned short)((x.u + 0x7FFFu + ((x.u >> 16) & 1u)) >> 16);
}
__device__ __forceinline__ unsigned pk_rh(float a, float b) { // lo=bf(a), hi=bf(b), half-up
  unsigned ua = __builtin_bit_cast(unsigned, a) + 0x8000u;
  unsigned ub = __builtin_bit_cast(unsigned, b) + 0x8000u;
  return __builtin_amdgcn_perm(ub, ua, 0x07060302);           // one v_perm_b32
}
__device__ __forceinline__ unsigned pk_rne(float a, float b) { // RNE both halves
  return (unsigned)f2bf_rn(a) | ((unsigned)f2bf_rn(b) << 16);
}

// ---- W fp32 -> bf16 (RNE) into workspace; 224*256*8 = 458752 elems exact
__global__ void wconv(const float* __restrict__ W, unsigned short* __restrict__ Wb) {
  int i = (blockIdx.x * 256 + threadIdx.x) * 8;
  float4 a = *(const float4*)(W + i);
  float4 c = *(const float4*)(W + i + 4);
  s16x8 r;
  r[0] = (short)f2bf_rn(a.x); r[1] = (short)f2bf_rn(a.y);
  r[2] = (short)f2bf_rn(a.z); r[3] = (short)f2bf_rn(a.w);
  r[4] = (short)f2bf_rn(c.x); r[5] = (short)f2bf_rn(c.y);
  r[6] = (short)f2bf_rn(c.z); r[7] = (short)f2bf_rn(c.w);
  *(s16x8*)(Wb + i) = r;
}

__device__ __forceinline__ bf16x8 ldw_f32(const float* p) {   // fallback path
  float4 a = *(const float4*)(p);
  float4 c = *(const float4*)(p + 4);
  u32x4 q;
  q[0] = pk_rh(a.x, a.y); q[1] = pk_rh(a.z, a.w);
  q[2] = pk_rh(c.x, c.y); q[3] = pk_rh(c.z, c.w);
  return __builtin_bit_cast(bf16x8, q);
}

template <bool USE_WB>
__global__ __launch_bounds__(256, 4)
void sgc_fused(const float* __restrict__ x, const float* __restrict__ Ag,
               const float* __restrict__ attA, const float* __restrict__ W,
               const unsigned short* __restrict__ Wb, const float* __restrict__ b,
               float* __restrict__ out) {
  const int tt   = blockIdx.x;        // 0..127  (t-tile of 4)
  const int n    = blockIdx.y;        // 0..7
  const int ch   = blockIdx.z;        // 0..1    (c-half: this block owns c in [ch*128, +128))
  const int tid  = threadIdx.x;
  const int wave = tid >> 6;
  const int lane = tid & 63;
  const int l15  = lane & 15;
  const int l4   = lane >> 4;

  // LDS: Zs0 [96][64] bf16 swz @0 (12288) | Zs1 @12288 (12288)
  //      Ms [176][32] bf16 @24576 (11264) | Ss [7][24] f32 @35840 (672) = 36512 B
  __shared__ __align__(16) char smem[36512];
  unsigned short* Zs0 = (unsigned short*)(smem);
  unsigned short* Zs1 = (unsigned short*)(smem + 12288);
  unsigned short* Ms  = (unsigned short*)(smem + 24576);
  float*          Ss  = (float*)(smem + 35840);
  float*          B2  = (float*)(smem);          // epilogue reuse: [128][25] f32 = 12800 B

  f32x4 acc[2][6];                               // 48 AGPRs
  #pragma unroll
  for (int i = 0; i < 2; ++i)
    #pragma unroll
    for (int j = 0; j < 6; ++j)
      acc[i][j] = (f32x4){0.f, 0.f, 0.f, 0.f};

  // ---- block init: M~[k][w][v] = M_k[v][w] bf16, zero-padded (v>=22 rows MUST be 0:
  //      they absorb the garbage/zero tail of the tv-linear ax fragments) ----
  for (int i = tid; i < MROWS * 32; i += 256) {
    int row = i >> 5, v = i & 31;
    int k = row / 24, w = row - k * 24;
    float val = 0.f;
    if (row < 168 && w < 22 && v < 22)
      val = (k < 3) ? Ag[(k * 22 + v) * 22 + w]
                    : attA[(((n << 2) + (k - 3)) * 22 + v) * 22 + w];
    Ms[i] = f2bf_rn(val);
  }
  if (tid < 168) {                               // S[k][w] = sum_v M_k[v][w] (fp32 exact)
    int k = tid / 24, w = tid - k * 24;
    float s = 0.f;
    if (w < 22)
      for (int v = 0; v < 22; ++v)
        s += (k < 3) ? Ag[(k * 22 + v) * 22 + w]
                     : attA[(((n << 2) + (k - 3)) * 22 + v) * 22 + w];
    Ss[tid] = s;
  }
  for (int i = tid; i < 512; i += 256) {         // tw 88..95 pad rows, both buffers
    Zs0[88 * CHUNK + i] = 0;
    Zs1[88 * CHUNK + i] = 0;
  }
  __syncthreads();

  const int ci0 = wave * 16 + l4 * 4;            // z-output row this thread owns
  const int cb  = ci0 >> 3, sub = ci0 & 7;
  int p = 0;                                     // Zs parity

  for (int chunk = 0; chunk < 4; ++chunk) {
    // ---- ax: global -> reg, tv-linear, bf16 RNE. Lane (l15,l4): row ci=wave*16+l15,
    //      elems kk=l4*8..+7 of t-block. Pairs with kk>=22 -> 0 (Ms rows are 0 there).
    //      float2 @ even elem index = 8B aligned; clamp keeps all loads in-tile. ----
    const float* xrow = x + (size_t)((n * 256 + chunk * CHUNK + wave * 16 + l15) * 11264)
                          + tt * NTW;
    bf16x8 ax[4];
    #pragma unroll
    for (int t = 0; t < 4; ++t) {
      u32x4 q;
      #pragma unroll
      for (int pp = 0; pp < 4; ++pp) {
        int kk = l4 * 8 + pp * 2;
        bool valid = (kk < 22);
        float2 v2 = *(const float2*)(xrow + t * 22 + (valid ? kk : 0));
        q[pp] = valid ? pk_rne(v2.x, v2.y) : 0u;
      }
      ax[t] = __builtin_bit_cast(bf16x8, q);
    }

    for (int k = 0; k < 7; ++k) {
      unsigned short* Zw = p ? Zs1 : Zs0;

      // ---- W-frag prefetch (global; latency covered by z-phase + barrier) ----
      bf16x8 wf[2][2];
      #pragma unroll
      for (int s = 0; s < 2; ++s)
        #pragma unroll
        for (int mi = 0; mi < 2; ++mi) {
          int c = ch * 128 + (wave * 2 + mi) * 16 + l15;
          size_t idx = (size_t)((k * 256 + c) * 256) + chunk * CHUNK + s * 32 + l4 * 8;
          wf[s][mi] = USE_WB ? *(const bf16x8*)(Wb + idx) : ldw_f32(W + idx);
        }

      // ---- z phase: z[ci,w] = X[ci,v] @ M_k[v,w]; ax from regs now ----
      bf16x8 bm0 = *(const bf16x8*)(&Ms[(k * 24 + l15) * 32 + l4 * 8]);
      bf16x8 bm1 = *(const bf16x8*)(&Ms[(k * 24 + 16 + l15) * 32 + l4 * 8]);
      #pragma unroll
      for (int th = 0; th < 2; ++th) {           // t-halves cap live zt at 16 VGPRs
        f32x4 zt[2][2];
        #pragma unroll
        for (int t2 = 0; t2 < 2; ++t2) {
          bf16x8 a = ax[th * 2 + t2];
          zt[t2][0] = __builtin_amdgcn_mfma_f32_16x16x32_bf16(a, bm0, (f32x4){0.f,0.f,0.f,0.f}, 0, 0, 0);
          zt[t2][1] = __builtin_amdgcn_mfma_f32_16x16x32_bf16(a, bm1, (f32x4){0.f,0.f,0.f,0.f}, 0, 0, 0);
        }
        #pragma unroll
        for (int t2 = 0; t2 < 2; ++t2) {
          int t = th * 2 + t2;
          #pragma unroll
          for (int ni = 0; ni < 2; ++ni) {
            int w = ni * 16 + l15;
            if (w < 22) {
              int tw = t * 22 + w;
              int eo = tw * CHUNK + ((cb ^ (tw & 7)) << 3) + sub;
              f32x4 z = zt[t2][ni];
              u32x2 pq; pq[0] = pk_rh(z[0], z[1]); pq[1] = pk_rh(z[2], z[3]);
              *(u32x2*)(&Zw[eo]) = pq;           // 8 B aligned, ~2-way banks
            }
          }
        }
      }
      __syncthreads();                           // the ONLY barrier per k

      // ---- main GEMM: out[c,tw] += Wk[c, ci-chunk] @ z ----
      __builtin_amdgcn_s_setprio(1);
      #pragma unroll
      for (int s = 0; s < 2; ++s) {
        int cb2 = (s << 2) + l4;
        #pragma unroll
        for (int ni = 0; ni < 6; ++ni) {
          int tw = ni * 16 + l15;
          bf16x8 zf = *(const bf16x8*)(&Zw[tw * CHUNK + ((cb2 ^ (tw & 7)) << 3)]);
          #pragma unroll
          for (int mi = 0; mi < 2; ++mi)
            acc[mi][ni] = __builtin_amdgcn_mfma_f32_16x16x32_bf16(wf[s][mi], zf, acc[mi][ni], 0, 0, 0);
        }
      }
      __builtin_amdgcn_s_setprio(0);
      p ^= 1;                                    // next z writes the other buffer
    }
  }
  __syncthreads();                               // all Zs reads done before B2 overwrites

  // ---- bias2[c_local][w] = sum_k b[k*256+c] * S_k[w] ----
  for (int i = tid; i < 128 * 22; i += 256) {
    int cl = i / 22, w = i - cl * 22;
    int c = ch * 128 + cl;
    float s = 0.f;
    #pragma unroll
    for (int k = 0; k < 7; ++k) s += b[k * 256 + c] * Ss[k * 24 + w];
    B2[cl * 25 + w] = s;
  }
  __syncthreads();

  // ---- epilogue: bias + store. C-layout: col=tw, row=l4*4+r ----
  int tg0 = tt * TT;
  #pragma unroll
  for (int ni = 0; ni < 6; ++ni) {
    int tw = ni * 16 + l15;
    if (tw < NTW) {
      int t = tw / 22, w = tw - t * 22;
      #pragma unroll
      for (int mi = 0; mi < 2; ++mi) {
        int cl0 = (wave * 2 + mi) * 16 + l4 * 4;
        #pragma unroll
        for (int r = 0; r < 4; ++r) {
          int cl = cl0 + r;
          int c = ch * 128 + cl;
          out[(size_t)((n * 256 + c) * 512 + tg0 + t) * 22 + w] = acc[mi][ni][r] + B2[cl * 25 + w];
        }
      }
    }
  }
}

extern "C" void kernel_launch(void* const* d_in, const int* in_sizes, int n_in,
                              void* d_out, int out_size, void* d_ws, size_t ws_size,
                              hipStream_t stream) {
  (void)in_sizes; (void)n_in; (void)out_size;
  const float* x    = (const float*)d_in[0];
  const float* Ag   = (const float*)d_in[1];
  const float* attA = (const float*)d_in[2];
  const float* W    = (const float*)d_in[3];
  const float* b    = (const float*)d_in[4];
  float* out = (float*)d_out;
  dim3 grid(128, 8, 2);    // (t-tiles, n, c-half)
  bool use_wb = (d_ws != nullptr) && (ws_size >= (size_t)WB_BYTES);
  if (use_wb) {
    unsigned short* Wb = (unsigned short*)d_ws;
    wconv<<<224, 256, 0, stream>>>(W, Wb);
    sgc_fused<true><<<grid, 256, 0, stream>>>(x, Ag, attA, W, Wb, b, out);
  } else {
    sgc_fused<false><<<grid, 256, 0, stream>>>(x, Ag, attA, W, nullptr, b, out);
  }
}

// Round 2
// 409.869 us; speedup vs baseline: 1.0517x; 1.0517x over previous
//
#include <hip/hip_runtime.h>

// S_GC_att_A round 6: t-split tile (TT=2) + double-buffered Zs + paired-u32 staging.
// R5 post-mortem (FAILED 332us): persistent ax[4] regs + wf[2][2] under bounds(256,4)
// -> spill (WRITE 119->207MB, FETCH 156->327MB, both unexplained by demand bytes).
// R6: pay for barrier reduction with LDS/tile-shape instead of registers:
//  - split t not c: NTW=44, full c=256 per block. z-work & x-reads no longer
//    duplicated across c-halves (z MFMA/block 896->448, x demand 184->92MB).
//  - Zs [48][64] x2 buffers = 12KB -> ONE barrier per k (61 -> 35 barriers/block).
//    LDS total 31392B -> still 4 blocks/CU.
//  - staging writes as paired u32 (even tv-pairs never straddle a row; 22 even).
//  - wf split per s (16 regs live at a time), no persistent ax. Peak ~110 regs.
//  - grid 2048 linear: n = bx&7 (8 n == 8 XCDs -> per-XCD x locality), tt = bx>>3.

#define NTW   44     // TT(2)*22
#define CHUNK 64
#define MROWS 176    // 7*24 + 8 pad rows
#define XSTR  56     // Xs row stride elems: 2*24 + 8 pad
#define WB_BYTES (7 * 256 * 256 * 2)

typedef __attribute__((ext_vector_type(8))) __bf16    bf16x8;
typedef __attribute__((ext_vector_type(4))) float     f32x4;
typedef __attribute__((ext_vector_type(8))) short     s16x8;
typedef __attribute__((ext_vector_type(2))) unsigned  u32x2;
typedef __attribute__((ext_vector_type(4))) unsigned  u32x4;

__device__ __forceinline__ unsigned short f2bf_rn(float f) {  // RNE
  union { float f; unsigned u; } x; x.f = f;
  return (unsigned short)((x.u + 0x7FFFu + ((x.u >> 16) & 1u)) >> 16);
}
__device__ __forceinline__ unsigned pk_rh(float a, float b) { // lo=bf(a), hi=bf(b), half-up
  unsigned ua = __builtin_bit_cast(unsigned, a) + 0x8000u;
  unsigned ub = __builtin_bit_cast(unsigned, b) + 0x8000u;
  return __builtin_amdgcn_perm(ub, ua, 0x07060302);           // one v_perm_b32
}
__device__ __forceinline__ unsigned pk_rne(float a, float b) { // RNE both halves
  return (unsigned)f2bf_rn(a) | ((unsigned)f2bf_rn(b) << 16);
}

// ---- W fp32 -> bf16 (RNE) into workspace; 224*256*8 = 458752 elems exact
__global__ void wconv(const float* __restrict__ W, unsigned short* __restrict__ Wb) {
  int i = (blockIdx.x * 256 + threadIdx.x) * 8;
  float4 a = *(const float4*)(W + i);
  float4 c = *(const float4*)(W + i + 4);
  s16x8 r;
  r[0] = (short)f2bf_rn(a.x); r[1] = (short)f2bf_rn(a.y);
  r[2] = (short)f2bf_rn(a.z); r[3] = (short)f2bf_rn(a.w);
  r[4] = (short)f2bf_rn(c.x); r[5] = (short)f2bf_rn(c.y);
  r[6] = (short)f2bf_rn(c.z); r[7] = (short)f2bf_rn(c.w);
  *(s16x8*)(Wb + i) = r;
}

__device__ __forceinline__ bf16x8 ldw_f32(const float* p) {   // fallback path
  float4 a = *(const float4*)(p);
  float4 c = *(const float4*)(p + 4);
  u32x4 q;
  q[0] = pk_rh(a.x, a.y); q[1] = pk_rh(a.z, a.w);
  q[2] = pk_rh(c.x, c.y); q[3] = pk_rh(c.z, c.w);
  return __builtin_bit_cast(bf16x8, q);
}

template <bool USE_WB>
__global__ __launch_bounds__(256, 4)
void sgc_fused(const float* __restrict__ x, const float* __restrict__ Ag,
               const float* __restrict__ attA, const float* __restrict__ W,
               const unsigned short* __restrict__ Wb, const float* __restrict__ b,
               float* __restrict__ out) {
  const int bx   = blockIdx.x;
  const int n    = bx & 7;            // 8 n == 8 XCDs: per-XCD x streaming locality
  const int tt   = bx >> 3;           // 0..255 (t-tile of 2)
  const int tid  = threadIdx.x;
  const int wave = tid >> 6;
  const int lane = tid & 63;
  const int l15  = lane & 15;
  const int l4   = lane >> 4;

  // LDS: Xs [64][56] bf16 @0 (7168) | Zs0 [48][64] swz @7168 (6144) | Zs1 @13312 (6144)
  //      Ms [176][32] bf16 @19456 (11264) | Ss [7][24] f32 @30720 (672) = 31392 B
  __shared__ __align__(16) char smem[31392];
  unsigned short* Xs  = (unsigned short*)(smem);
  unsigned short* Zs0 = (unsigned short*)(smem + 7168);
  unsigned short* Zs1 = (unsigned short*)(smem + 13312);
  unsigned short* Ms  = (unsigned short*)(smem + 19456);
  float*          Ss  = (float*)(smem + 30720);
  float*          B2  = (float*)(smem);          // epilogue reuse: [256][25] f32 = 25600 B

  f32x4 acc[4][3];                               // 48 AGPRs
  #pragma unroll
  for (int i = 0; i < 4; ++i)
    #pragma unroll
    for (int j = 0; j < 3; ++j)
      acc[i][j] = (f32x4){0.f, 0.f, 0.f, 0.f};

  // ---- block init: M~[k][w][v] = M_k[v][w] bf16, zero-padded (w/v >= 22 rows/cols 0;
  //      pad rows absorb the v=22..31 tail of ax fragments and w=22..31 of bm1) ----
  for (int i = tid; i < MROWS * 32; i += 256) {
    int row = i >> 5, v = i & 31;
    int k = row / 24, w = row - k * 24;
    float val = 0.f;
    if (row < 168 && w < 22 && v < 22)
      val = (k < 3) ? Ag[(k * 22 + v) * 22 + w]
                    : attA[(((n << 2) + (k - 3)) * 22 + v) * 22 + w];
    Ms[i] = f2bf_rn(val);
  }
  if (tid < 168) {                               // S[k][w] = sum_v M_k[v][w] (fp32 exact)
    int k = tid / 24, w = tid - k * 24;
    float s = 0.f;
    if (w < 22)
      for (int v = 0; v < 22; ++v)
        s += (k < 3) ? Ag[(k * 22 + v) * 22 + w]
                     : attA[(((n << 2) + (k - 3)) * 22 + v) * 22 + w];
    Ss[tid] = s;
  }
  Zs0[44 * CHUNK + tid] = 0;                     // pad rows 44..47, both buffers (256 elems)
  Zs1[44 * CHUNK + tid] = 0;
  for (int i = tid; i < 64 * XSTR / 2; i += 256) // Xs zero (unwritten pad cols -> finite)
    ((unsigned*)Xs)[i] = 0;
  __syncthreads();

  const int ci0 = wave * 16 + l4 * 4;            // z-output row this thread owns
  const int cb  = ci0 >> 3, sub = ci0 & 7;
  int p = 0;                                     // Zs parity

  for (int chunk = 0; chunk < 4; ++chunk) {
    // ---- stage x[n, chunk*64..+64, tt*2..+2, :] -> Xs bf16 [ci][t*24+v], u32 pairs ----
    for (int i = tid; i < 64 * 11; i += 256) {
      int ci = i / 11, q = i - ci * 11;
      const float4 f4 = *(const float4*)(x + (size_t)((n * 256 + chunk * CHUNK + ci) * 11264)
                                           + tt * NTW + q * 4);
      int tv0 = q * 4;                           // even -> pairs never straddle a t-row
      int t0 = tv0 / 22, v0 = tv0 - t0 * 22;
      ((unsigned*)Xs)[ci * 28 + t0 * 12 + (v0 >> 1)] = pk_rne(f4.x, f4.y);
      int tv2 = tv0 + 2;
      int t2 = tv2 / 22, v2 = tv2 - t2 * 22;
      ((unsigned*)Xs)[ci * 28 + t2 * 12 + (v2 >> 1)] = pk_rne(f4.z, f4.w);
    }
    __syncthreads();

    for (int k = 0; k < 7; ++k) {
      unsigned short* Zw = p ? Zs1 : Zs0;

      // ---- wf s=0 prefetch (global; drained before main s=0) ----
      bf16x8 wf0[4];
      #pragma unroll
      for (int mi = 0; mi < 4; ++mi) {
        int c = (wave * 4 + mi) * 16 + l15;
        size_t idx = (size_t)((k * 256 + c) * 256) + chunk * CHUNK + l4 * 8;
        wf0[mi] = USE_WB ? *(const bf16x8*)(Wb + idx) : ldw_f32(W + idx);
      }

      // ---- z phase: z[ci,w] = X[ci,v] @ M_k[v,w]; wave owns ci rows [wave*16,+16) ----
      bf16x8 bm0 = *(const bf16x8*)(&Ms[(k * 24 + l15) * 32 + l4 * 8]);
      bf16x8 bm1 = *(const bf16x8*)(&Ms[(k * 24 + 16 + l15) * 32 + l4 * 8]);
      #pragma unroll
      for (int t = 0; t < 2; ++t) {
        bf16x8 a = *(const bf16x8*)(&Xs[(wave * 16 + l15) * XSTR + t * 24 + l4 * 8]);
        f32x4 z0 = __builtin_amdgcn_mfma_f32_16x16x32_bf16(a, bm0, (f32x4){0.f,0.f,0.f,0.f}, 0, 0, 0);
        f32x4 z1 = __builtin_amdgcn_mfma_f32_16x16x32_bf16(a, bm1, (f32x4){0.f,0.f,0.f,0.f}, 0, 0, 0);
        int tw0 = t * 22 + l15;                  // w = l15 < 22 always
        u32x2 p0; p0[0] = pk_rh(z0[0], z0[1]); p0[1] = pk_rh(z0[2], z0[3]);
        *(u32x2*)(&Zw[tw0 * CHUNK + ((cb ^ (tw0 & 7)) << 3) + sub]) = p0;
        if (l15 < 6) {                           // w = 16+l15 < 22
          int tw1 = t * 22 + 16 + l15;
          u32x2 p1; p1[0] = pk_rh(z1[0], z1[1]); p1[1] = pk_rh(z1[2], z1[3]);
          *(u32x2*)(&Zw[tw1 * CHUNK + ((cb ^ (tw1 & 7)) << 3) + sub]) = p1;
        }
      }

      // ---- wf s=1 issue (latency hidden by barrier + main s=0) ----
      bf16x8 wf1[4];
      #pragma unroll
      for (int mi = 0; mi < 4; ++mi) {
        int c = (wave * 4 + mi) * 16 + l15;
        size_t idx = (size_t)((k * 256 + c) * 256) + chunk * CHUNK + 32 + l4 * 8;
        wf1[mi] = USE_WB ? *(const bf16x8*)(Wb + idx) : ldw_f32(W + idx);
      }
      __syncthreads();                           // the ONLY barrier per k

      // ---- main GEMM: out[c,tw] += Wk[c, ci-chunk] @ z ----
      __builtin_amdgcn_s_setprio(1);
      #pragma unroll
      for (int ni = 0; ni < 3; ++ni) {
        int tw = ni * 16 + l15;
        bf16x8 zf = *(const bf16x8*)(&Zw[tw * CHUNK + ((l4 ^ (tw & 7)) << 3)]);
        #pragma unroll
        for (int mi = 0; mi < 4; ++mi)
          acc[mi][ni] = __builtin_amdgcn_mfma_f32_16x16x32_bf16(wf0[mi], zf, acc[mi][ni], 0, 0, 0);
      }
      #pragma unroll
      for (int ni = 0; ni < 3; ++ni) {
        int tw = ni * 16 + l15;
        bf16x8 zf = *(const bf16x8*)(&Zw[tw * CHUNK + (((4 + l4) ^ (tw & 7)) << 3)]);
        #pragma unroll
        for (int mi = 0; mi < 4; ++mi)
          acc[mi][ni] = __builtin_amdgcn_mfma_f32_16x16x32_bf16(wf1[mi], zf, acc[mi][ni], 0, 0, 0);
      }
      __builtin_amdgcn_s_setprio(0);
      p ^= 1;                                    // next z writes the other buffer
    }
  }
  __syncthreads();                               // all Zs/Xs reads done before B2 overwrites

  // ---- bias2[c][w] = sum_k b[k*256+c] * S_k[w] ----
  for (int i = tid; i < 256 * 22; i += 256) {
    int cl = i / 22, w = i - cl * 22;
    float s = 0.f;
    #pragma unroll
    for (int k = 0; k < 7; ++k) s += b[k * 256 + cl] * Ss[k * 24 + w];
    B2[cl * 25 + w] = s;
  }
  __syncthreads();

  // ---- epilogue: bias + store. C-layout: col=tw, row=l4*4+r ----
  int tg0 = tt * 2;
  #pragma unroll
  for (int ni = 0; ni < 3; ++ni) {
    int tw = ni * 16 + l15;
    if (tw < NTW) {
      int t = tw / 22, w = tw - t * 22;
      #pragma unroll
      for (int mi = 0; mi < 4; ++mi) {
        int cl0 = (wave * 4 + mi) * 16 + l4 * 4;
        #pragma unroll
        for (int r = 0; r < 4; ++r) {
          int c = cl0 + r;
          out[(size_t)((n * 256 + c) * 512 + tg0 + t) * 22 + w] = acc[mi][ni][r] + B2[c * 25 + w];
        }
      }
    }
  }
}

extern "C" void kernel_launch(void* const* d_in, const int* in_sizes, int n_in,
                              void* d_out, int out_size, void* d_ws, size_t ws_size,
                              hipStream_t stream) {
  (void)in_sizes; (void)n_in; (void)out_size;
  const float* x    = (const float*)d_in[0];
  const float* Ag   = (const float*)d_in[1];
  const float* attA = (const float*)d_in[2];
  const float* W    = (const float*)d_in[3];
  const float* b    = (const float*)d_in[4];
  float* out = (float*)d_out;
  dim3 grid(2048);         // linear: n = bx&7 (XCD-aligned), tt = bx>>3
  bool use_wb = (d_ws != nullptr) && (ws_size >= (size_t)WB_BYTES);
  if (use_wb) {
    unsigned short* Wb = (unsigned short*)d_ws;
    wconv<<<224, 256, 0, stream>>>(W, Wb);
    sgc_fused<true><<<grid, 256, 0, stream>>>(x, Ag, attA, W, Wb, b, out);
  } else {
    sgc_fused<false><<<grid, 256, 0, stream>>>(x, Ag, attA, W, nullptr, b, out);
  }
}

// Round 3
// 291.282 us; speedup vs baseline: 1.4799x; 1.4071x over previous
//
#include <hip/hip_runtime.h>

// S_GC_att_A round 7: R4 (203us, best) + two surgically-isolated, R6-validated deltas.
// R5 post-mortem (332us): persistent ax regs -> spill. R6 post-mortem (304us): z-phase
// halved + wf1 issued with zero cover before the vmcnt(0)+barrier drain + per-block
// work halved -> worse latency amortization. Both structural rewrites lost to R4.
// R7 keeps R4's exact 4-wave / TT=4 / c-split / single-Zs / 2-barrier structure and
// changes ONLY:
//  (1) staging: scalar f2bf+u16-writes -> paired pk_rh u32 writes (validated in R6:
//      VALU-time -21%, conflicts -36%). Staging was ~70% of R4's 70us VALU time.
//  (2) grid: 3D -> 1D flat = n + 8*ch + 16*tt, so XCD == n; the two ch-halves of an
//      (n,tt) are co-resident on one XCD and share the x tile via L2 (R6: FETCH
//      156->70MB), adjacent tt share out-row boundary lines.

#define TT    4
#define NTW   88     // TT*22
#define XSTR  104    // Xs row stride in bf16 (4*24 + 8 pad)
#define MROWS 176    // 7*24 + 8 pad rows
#define CHUNK 64
#define WB_BYTES (7 * 256 * 256 * 2)

typedef __attribute__((ext_vector_type(8))) __bf16    bf16x8;
typedef __attribute__((ext_vector_type(4))) float     f32x4;
typedef __attribute__((ext_vector_type(8))) short     s16x8;
typedef __attribute__((ext_vector_type(2))) unsigned  u32x2;
typedef __attribute__((ext_vector_type(4))) unsigned  u32x4;

__device__ __forceinline__ unsigned short f2bf_rn(float f) {  // RNE
  union { float f; unsigned u; } x; x.f = f;
  return (unsigned short)((x.u + 0x7FFFu + ((x.u >> 16) & 1u)) >> 16);
}
__device__ __forceinline__ unsigned pk_rh(float a, float b) { // lo=bf(a), hi=bf(b), half-up
  unsigned ua = __builtin_bit_cast(unsigned, a) + 0x8000u;
  unsigned ub = __builtin_bit_cast(unsigned, b) + 0x8000u;
  return __builtin_amdgcn_perm(ub, ua, 0x07060302);           // one v_perm_b32
}

// ---- W fp32 -> bf16 (RNE) into workspace; 224*256*8 = 458752 elems exact
__global__ void wconv(const float* __restrict__ W, unsigned short* __restrict__ Wb) {
  int i = (blockIdx.x * 256 + threadIdx.x) * 8;
  float4 a = *(const float4*)(W + i);
  float4 c = *(const float4*)(W + i + 4);
  s16x8 r;
  r[0] = (short)f2bf_rn(a.x); r[1] = (short)f2bf_rn(a.y);
  r[2] = (short)f2bf_rn(a.z); r[3] = (short)f2bf_rn(a.w);
  r[4] = (short)f2bf_rn(c.x); r[5] = (short)f2bf_rn(c.y);
  r[6] = (short)f2bf_rn(c.z); r[7] = (short)f2bf_rn(c.w);
  *(s16x8*)(Wb + i) = r;
}

__device__ __forceinline__ bf16x8 ldw_f32(const float* p) {   // fallback path
  float4 a = *(const float4*)(p);
  float4 c = *(const float4*)(p + 4);
  u32x4 q;
  q[0] = pk_rh(a.x, a.y); q[1] = pk_rh(a.z, a.w);
  q[2] = pk_rh(c.x, c.y); q[3] = pk_rh(c.z, c.w);
  return __builtin_bit_cast(bf16x8, q);
}

template <bool USE_WB>
__global__ __launch_bounds__(256, 4)
void sgc_fused(const float* __restrict__ x, const float* __restrict__ Ag,
               const float* __restrict__ attA, const float* __restrict__ W,
               const unsigned short* __restrict__ Wb, const float* __restrict__ b,
               float* __restrict__ out) {
  const int bx   = blockIdx.x;
  const int n    = bx & 7;            // XCD == n (x-tile L2 sharing across ch, tt)
  const int ch   = (bx >> 3) & 1;     // c-half: this block owns c in [ch*128, +128)
  const int tt   = bx >> 4;           // 0..127  (t-tile of 4)
  const int tid  = threadIdx.x;
  const int wave = tid >> 6;
  const int lane = tid & 63;
  const int l15  = lane & 15;
  const int l4   = lane >> 4;

  // LDS: Xs [64][104] bf16 @0 (13312) | Zs [96][64] bf16 swizzled @13312 (12288)
  //      Ms [176][32] bf16 @25600 (11264) | Ss [7][24] f32 @36864 (672) = 37536 B
  __shared__ __align__(16) char smem[37536];
  unsigned short* Xs = (unsigned short*)(smem);
  unsigned short* Zs = (unsigned short*)(smem + 13312);
  unsigned short* Ms = (unsigned short*)(smem + 25600);
  float*          Ss = (float*)(smem + 36864);
  float*          B2 = (float*)(smem);           // epilogue reuse: [128][25] f32 = 12800 B

  f32x4 acc[2][6];                               // 48 AGPRs
  #pragma unroll
  for (int i = 0; i < 2; ++i)
    #pragma unroll
    for (int j = 0; j < 6; ++j)
      acc[i][j] = (f32x4){0.f, 0.f, 0.f, 0.f};

  // ---- block init: M~[k][w][v] = M_k[v][w] bf16, zero-padded ----
  for (int i = tid; i < MROWS * 32; i += 256) {
    int row = i >> 5, v = i & 31;
    int k = row / 24, w = row - k * 24;
    float val = 0.f;
    if (row < 168 && w < 22 && v < 22)
      val = (k < 3) ? Ag[(k * 22 + v) * 22 + w]
                    : attA[(((n << 2) + (k - 3)) * 22 + v) * 22 + w];
    Ms[i] = f2bf_rn(val);
  }
  if (tid < 168) {                               // S[k][w] = sum_v M_k[v][w] (fp32 exact)
    int k = tid / 24, w = tid - k * 24;
    float s = 0.f;
    if (w < 22)
      for (int v = 0; v < 22; ++v)
        s += (k < 3) ? Ag[(k * 22 + v) * 22 + w]
                     : attA[(((n << 2) + (k - 3)) * 22 + v) * 22 + w];
    Ss[tid] = s;
  }
  for (int i = tid; i < 512; i += 256) Zs[88 * CHUNK + i] = 0;   // Ntile-5 pad rows
  for (int i = tid; i < 64 * XSTR / 2; i += 256) ((unsigned*)Xs)[i] = 0; // pads 0, not NaN
  __syncthreads();

  for (int chunk = 0; chunk < 4; ++chunk) {
    // ---- stage x[n, chunk*64..+64, tt*4..+4, :] -> Xs bf16 [ci][t*24+v] ----
    // paired u32 writes: tv pairs at even offsets never straddle a t-row (22 even),
    // and (t*24+v0) even -> 4B-aligned. pk_rh == RNE except on exact-tie patterns.
    for (int i = tid; i < CHUNK * 22; i += 256) {
      int ci = i / 22, q = i - ci * 22;
      const float4 f4 = *(const float4*)(x + (size_t)((n * 256 + chunk * CHUNK + ci) * 11264)
                                           + tt * NTW + q * 4);
      int tv0 = q * 4;
      int t0 = tv0 / 22, v0 = tv0 - t0 * 22;
      ((unsigned*)Xs)[ci * 52 + t0 * 12 + (v0 >> 1)] = pk_rh(f4.x, f4.y);
      int tv2 = tv0 + 2;
      int t2 = tv2 / 22, v2 = tv2 - t2 * 22;
      ((unsigned*)Xs)[ci * 52 + t2 * 12 + (v2 >> 1)] = pk_rh(f4.z, f4.w);
    }
    __syncthreads();

    for (int k = 0; k < 7; ++k) {
      // ---- W-frag prefetch (global; drained by barrier #1, consumed after) ----
      bf16x8 wf[2][2];
      #pragma unroll
      for (int s = 0; s < 2; ++s)
        #pragma unroll
        for (int mi = 0; mi < 2; ++mi) {
          int c = ch * 128 + (wave * 2 + mi) * 16 + l15;
          size_t idx = (size_t)((k * 256 + c) * 256) + chunk * CHUNK + s * 32 + l4 * 8;
          wf[s][mi] = USE_WB ? *(const bf16x8*)(Wb + idx) : ldw_f32(W + idx);
        }

      // ---- z phase: z[ci,w] = X[ci,v] @ M_k[v,w]; wave owns ci rows [wave*16,+16) ----
      bf16x8 bm0 = *(const bf16x8*)(&Ms[(k * 24 + l15) * 32 + l4 * 8]);
      bf16x8 bm1 = *(const bf16x8*)(&Ms[(k * 24 + 16 + l15) * 32 + l4 * 8]);
      const int ci0 = wave * 16 + l4 * 4;
      const int cb  = ci0 >> 3, sub = ci0 & 7;
      #pragma unroll
      for (int th = 0; th < 2; ++th) {           // t-halves cap live zt at 16 VGPRs
        f32x4 zt[2][2];
        #pragma unroll
        for (int t2 = 0; t2 < 2; ++t2) {
          int t = th * 2 + t2;
          bf16x8 ax = *(const bf16x8*)(&Xs[(wave * 16 + l15) * XSTR + t * 24 + l4 * 8]);
          zt[t2][0] = __builtin_amdgcn_mfma_f32_16x16x32_bf16(ax, bm0, (f32x4){0.f,0.f,0.f,0.f}, 0, 0, 0);
          zt[t2][1] = __builtin_amdgcn_mfma_f32_16x16x32_bf16(ax, bm1, (f32x4){0.f,0.f,0.f,0.f}, 0, 0, 0);
        }
        #pragma unroll
        for (int t2 = 0; t2 < 2; ++t2) {
          int t = th * 2 + t2;
          #pragma unroll
          for (int ni = 0; ni < 2; ++ni) {
            int w = ni * 16 + l15;
            if (w < 22) {
              int tw = t * 22 + w;
              int eo = tw * CHUNK + ((cb ^ (tw & 7)) << 3) + sub;
              f32x4 z = zt[t2][ni];
              u32x2 p; p[0] = pk_rh(z[0], z[1]); p[1] = pk_rh(z[2], z[3]);
              *(u32x2*)(&Zs[eo]) = p;            // 8 B aligned, ~2-way banks
            }
          }
        }
      }
      __syncthreads();

      // ---- main GEMM: out[c,tw] += Wk[c, ci-chunk] @ z ----
      #pragma unroll
      for (int s = 0; s < 2; ++s) {
        int cb2 = (s << 2) + l4;
        #pragma unroll
        for (int ni = 0; ni < 6; ++ni) {
          int tw = ni * 16 + l15;
          bf16x8 zf = *(const bf16x8*)(&Zs[tw * CHUNK + ((cb2 ^ (tw & 7)) << 3)]);
          #pragma unroll
          for (int mi = 0; mi < 2; ++mi)
            acc[mi][ni] = __builtin_amdgcn_mfma_f32_16x16x32_bf16(wf[s][mi], zf, acc[mi][ni], 0, 0, 0);
        }
      }
      __syncthreads();   // protects Zs overwrite (next k) / Xs overwrite (next chunk)
    }
  }

  // ---- bias2[c_local][w] = sum_k b[k*256+c] * S_k[w]  (Xs+Zs dead -> reuse) ----
  for (int i = tid; i < 128 * 22; i += 256) {
    int cl = i / 22, w = i - cl * 22;
    int c = ch * 128 + cl;
    float s = 0.f;
    #pragma unroll
    for (int k = 0; k < 7; ++k) s += b[k * 256 + c] * Ss[k * 24 + w];
    B2[cl * 25 + w] = s;
  }
  __syncthreads();

  // ---- epilogue: bias + store. C-layout: col=tw, row=l4*4+r ----
  int tg0 = tt * TT;
  #pragma unroll
  for (int ni = 0; ni < 6; ++ni) {
    int tw = ni * 16 + l15;
    if (tw < NTW) {
      int t = tw / 22, w = tw - t * 22;
      #pragma unroll
      for (int mi = 0; mi < 2; ++mi) {
        int cl0 = (wave * 2 + mi) * 16 + l4 * 4;
        #pragma unroll
        for (int r = 0; r < 4; ++r) {
          int cl = cl0 + r;
          int c = ch * 128 + cl;
          out[(size_t)((n * 256 + c) * 512 + tg0 + t) * 22 + w] = acc[mi][ni][r] + B2[cl * 25 + w];
        }
      }
    }
  }
}

extern "C" void kernel_launch(void* const* d_in, const int* in_sizes, int n_in,
                              void* d_out, int out_size, void* d_ws, size_t ws_size,
                              hipStream_t stream) {
  (void)in_sizes; (void)n_in; (void)out_size;
  const float* x    = (const float*)d_in[0];
  const float* Ag   = (const float*)d_in[1];
  const float* attA = (const float*)d_in[2];
  const float* W    = (const float*)d_in[3];
  const float* b    = (const float*)d_in[4];
  float* out = (float*)d_out;
  dim3 grid(2048);         // flat = n + 8*ch + 16*tt  (XCD == n)
  bool use_wb = (d_ws != nullptr) && (ws_size >= (size_t)WB_BYTES);
  if (use_wb) {
    unsigned short* Wb = (unsigned short*)d_ws;
    wconv<<<224, 256, 0, stream>>>(W, Wb);
    sgc_fused<true><<<grid, 256, 0, stream>>>(x, Ag, attA, W, Wb, b, out);
  } else {
    sgc_fused<false><<<grid, 256, 0, stream>>>(x, Ag, attA, W, nullptr, b, out);
  }
}

// Round 4
// 278.904 us; speedup vs baseline: 1.5456x; 1.0444x over previous
//
#include <hip/hip_runtime.h>

// S_GC_att_A round 8: merge the two c-half blocks -> one 512-thread / 8-wave block.
// R7 (189us, best): c-split duplicated the z-phase (z = X@M_k identical in both
// ch-blocks) = 25% of device MFMA, plus 2x staging + 2x Ms-init. R8 keeps R7's
// per-wave inner loop byte-for-byte (same z swizzle, same wf prefetch, same main
// GEMM shape, same 48-AGPR acc, 2 barriers/k) and only remaps wave->role:
//   z-phase: wave (g=wave&3, h=wave>>2) does ci rows [g*16,+16) x t in {2h,2h+1}
//            (4 MFMA/wave; 8 waves cover all 64 ci x 4 t once).
//   main:    wave owns c strip [wave*32,+32) (mi 0..1), full c=256 per block.
// MFMA total -12.5%, staging/init halved. LDS unchanged 37536B. bounds(512,4):
// 2 blocks/CU x 8 waves = 16 waves/CU (same ceiling as R7). Grid 1024, XCD==n.
// Tripwires: VGPR>64 / WRITE>100MB => spill; Occupancy<35% => diversity loss.

#define TT    4
#define NTW   88     // TT*22
#define XSTR  104    // Xs row stride in bf16 (4*24 + 8 pad)
#define MROWS 176    // 7*24 + 8 pad rows
#define CHUNK 64
#define WB_BYTES (7 * 256 * 256 * 2)

typedef __attribute__((ext_vector_type(8))) __bf16    bf16x8;
typedef __attribute__((ext_vector_type(4))) float     f32x4;
typedef __attribute__((ext_vector_type(8))) short     s16x8;
typedef __attribute__((ext_vector_type(2))) unsigned  u32x2;
typedef __attribute__((ext_vector_type(4))) unsigned  u32x4;

__device__ __forceinline__ unsigned short f2bf_rn(float f) {  // RNE
  union { float f; unsigned u; } x; x.f = f;
  return (unsigned short)((x.u + 0x7FFFu + ((x.u >> 16) & 1u)) >> 16);
}
__device__ __forceinline__ unsigned pk_rh(float a, float b) { // lo=bf(a), hi=bf(b), half-up
  unsigned ua = __builtin_bit_cast(unsigned, a) + 0x8000u;
  unsigned ub = __builtin_bit_cast(unsigned, b) + 0x8000u;
  return __builtin_amdgcn_perm(ub, ua, 0x07060302);           // one v_perm_b32
}

// ---- W fp32 -> bf16 (RNE) into workspace; 224*256*8 = 458752 elems exact
__global__ void wconv(const float* __restrict__ W, unsigned short* __restrict__ Wb) {
  int i = (blockIdx.x * 256 + threadIdx.x) * 8;
  float4 a = *(const float4*)(W + i);
  float4 c = *(const float4*)(W + i + 4);
  s16x8 r;
  r[0] = (short)f2bf_rn(a.x); r[1] = (short)f2bf_rn(a.y);
  r[2] = (short)f2bf_rn(a.z); r[3] = (short)f2bf_rn(a.w);
  r[4] = (short)f2bf_rn(c.x); r[5] = (short)f2bf_rn(c.y);
  r[6] = (short)f2bf_rn(c.z); r[7] = (short)f2bf_rn(c.w);
  *(s16x8*)(Wb + i) = r;
}

__device__ __forceinline__ bf16x8 ldw_f32(const float* p) {   // fallback path
  float4 a = *(const float4*)(p);
  float4 c = *(const float4*)(p + 4);
  u32x4 q;
  q[0] = pk_rh(a.x, a.y); q[1] = pk_rh(a.z, a.w);
  q[2] = pk_rh(c.x, c.y); q[3] = pk_rh(c.z, c.w);
  return __builtin_bit_cast(bf16x8, q);
}

template <bool USE_WB>
__global__ __launch_bounds__(512, 4)
void sgc_fused(const float* __restrict__ x, const float* __restrict__ Ag,
               const float* __restrict__ attA, const float* __restrict__ W,
               const unsigned short* __restrict__ Wb, const float* __restrict__ b,
               float* __restrict__ out) {
  const int bx   = blockIdx.x;
  const int n    = bx & 7;            // XCD == n (x-tile L2 sharing across tt)
  const int tt   = bx >> 3;           // 0..127  (t-tile of 4)
  const int tid  = threadIdx.x;
  const int wave = tid >> 6;          // 0..7
  const int lane = tid & 63;
  const int l15  = lane & 15;
  const int l4   = lane >> 4;
  const int g    = wave & 3;          // z-phase ci-group
  const int h    = wave >> 2;         // z-phase t-half

  // LDS: Xs [64][104] bf16 @0 (13312) | Zs [96][64] bf16 swizzled @13312 (12288)
  //      Ms [176][32] bf16 @25600 (11264) | Ss [7][24] f32 @36864 (672) = 37536 B
  __shared__ __align__(16) char smem[37536];
  unsigned short* Xs = (unsigned short*)(smem);
  unsigned short* Zs = (unsigned short*)(smem + 13312);
  unsigned short* Ms = (unsigned short*)(smem + 25600);
  float*          Ss = (float*)(smem + 36864);
  float*          B2 = (float*)(smem);           // epilogue reuse: [256][25] f32 = 25600 B

  f32x4 acc[2][6];                               // 48 AGPRs
  #pragma unroll
  for (int i = 0; i < 2; ++i)
    #pragma unroll
    for (int j = 0; j < 6; ++j)
      acc[i][j] = (f32x4){0.f, 0.f, 0.f, 0.f};

  // ---- block init: M~[k][w][v] = M_k[v][w] bf16, zero-padded ----
  for (int i = tid; i < MROWS * 32; i += 512) {
    int row = i >> 5, v = i & 31;
    int k = row / 24, w = row - k * 24;
    float val = 0.f;
    if (row < 168 && w < 22 && v < 22)
      val = (k < 3) ? Ag[(k * 22 + v) * 22 + w]
                    : attA[(((n << 2) + (k - 3)) * 22 + v) * 22 + w];
    Ms[i] = f2bf_rn(val);
  }
  if (tid < 168) {                               // S[k][w] = sum_v M_k[v][w] (fp32 exact)
    int k = tid / 24, w = tid - k * 24;
    float s = 0.f;
    if (w < 22)
      for (int v = 0; v < 22; ++v)
        s += (k < 3) ? Ag[(k * 22 + v) * 22 + w]
                     : attA[(((n << 2) + (k - 3)) * 22 + v) * 22 + w];
    Ss[tid] = s;
  }
  Zs[88 * CHUNK + tid] = 0;                      // pad rows 88..95: 512 elems exactly
  for (int i = tid; i < 64 * XSTR / 2; i += 512) ((unsigned*)Xs)[i] = 0; // pads 0, not NaN
  __syncthreads();

  const int ci0 = g * 16 + l4 * 4;               // z-output row this thread owns
  const int cb  = ci0 >> 3, sub = ci0 & 7;

  for (int chunk = 0; chunk < 4; ++chunk) {
    // ---- stage x[n, chunk*64..+64, tt*4..+4, :] -> Xs bf16 [ci][t*24+v] ----
    // paired u32 writes: tv pairs at even offsets never straddle a t-row (22 even).
    for (int i = tid; i < CHUNK * 22; i += 512) {
      int ci = i / 22, q = i - ci * 22;
      const float4 f4 = *(const float4*)(x + (size_t)((n * 256 + chunk * CHUNK + ci) * 11264)
                                           + tt * NTW + q * 4);
      int tv0 = q * 4;
      int t0 = tv0 / 22, v0 = tv0 - t0 * 22;
      ((unsigned*)Xs)[ci * 52 + t0 * 12 + (v0 >> 1)] = pk_rh(f4.x, f4.y);
      int tv2 = tv0 + 2;
      int t2 = tv2 / 22, v2 = tv2 - t2 * 22;
      ((unsigned*)Xs)[ci * 52 + t2 * 12 + (v2 >> 1)] = pk_rh(f4.z, f4.w);
    }
    __syncthreads();

    for (int k = 0; k < 7; ++k) {
      // ---- W-frag prefetch (global; drained by barrier #1, consumed in main) ----
      bf16x8 wf[2][2];
      #pragma unroll
      for (int s = 0; s < 2; ++s)
        #pragma unroll
        for (int mi = 0; mi < 2; ++mi) {
          int c = wave * 32 + mi * 16 + l15;
          size_t idx = (size_t)((k * 256 + c) * 256) + chunk * CHUNK + s * 32 + l4 * 8;
          wf[s][mi] = USE_WB ? *(const bf16x8*)(Wb + idx) : ldw_f32(W + idx);
        }

      // ---- z phase: z[ci,w] = X[ci,v] @ M_k[v,w]; wave (g,h): rows [g*16,+16),
      //      t in {2h, 2h+1}. 8 waves cover all 64 ci x 4 t exactly once. ----
      bf16x8 bm0 = *(const bf16x8*)(&Ms[(k * 24 + l15) * 32 + l4 * 8]);
      bf16x8 bm1 = *(const bf16x8*)(&Ms[(k * 24 + 16 + l15) * 32 + l4 * 8]);
      f32x4 zt[2][2];
      #pragma unroll
      for (int t2 = 0; t2 < 2; ++t2) {
        int t = h * 2 + t2;
        bf16x8 ax = *(const bf16x8*)(&Xs[(g * 16 + l15) * XSTR + t * 24 + l4 * 8]);
        zt[t2][0] = __builtin_amdgcn_mfma_f32_16x16x32_bf16(ax, bm0, (f32x4){0.f,0.f,0.f,0.f}, 0, 0, 0);
        zt[t2][1] = __builtin_amdgcn_mfma_f32_16x16x32_bf16(ax, bm1, (f32x4){0.f,0.f,0.f,0.f}, 0, 0, 0);
      }
      #pragma unroll
      for (int t2 = 0; t2 < 2; ++t2) {
        int t = h * 2 + t2;
        #pragma unroll
        for (int ni = 0; ni < 2; ++ni) {
          int w = ni * 16 + l15;
          if (w < 22) {
            int tw = t * 22 + w;
            int eo = tw * CHUNK + ((cb ^ (tw & 7)) << 3) + sub;
            f32x4 z = zt[t2][ni];
            u32x2 p; p[0] = pk_rh(z[0], z[1]); p[1] = pk_rh(z[2], z[3]);
            *(u32x2*)(&Zs[eo]) = p;              // 8 B aligned, ~2-way banks
          }
        }
      }
      __syncthreads();

      // ---- main GEMM: out[c,tw] += Wk[c, ci-chunk] @ z; wave owns c [wave*32,+32) ----
      #pragma unroll
      for (int s = 0; s < 2; ++s) {
        int cb2 = (s << 2) + l4;
        #pragma unroll
        for (int ni = 0; ni < 6; ++ni) {
          int tw = ni * 16 + l15;
          bf16x8 zf = *(const bf16x8*)(&Zs[tw * CHUNK + ((cb2 ^ (tw & 7)) << 3)]);
          #pragma unroll
          for (int mi = 0; mi < 2; ++mi)
            acc[mi][ni] = __builtin_amdgcn_mfma_f32_16x16x32_bf16(wf[s][mi], zf, acc[mi][ni], 0, 0, 0);
        }
      }
      __syncthreads();   // protects Zs overwrite (next k) / Xs overwrite (next chunk)
    }
  }

  // ---- bias2[c][w] = sum_k b[k*256+c] * S_k[w]  (Xs+Zs dead -> reuse) ----
  for (int i = tid; i < 256 * 22; i += 512) {
    int cl = i / 22, w = i - cl * 22;
    float s = 0.f;
    #pragma unroll
    for (int k = 0; k < 7; ++k) s += b[k * 256 + cl] * Ss[k * 24 + w];
    B2[cl * 25 + w] = s;
  }
  __syncthreads();

  // ---- epilogue: bias + store. C-layout: col=tw, row=l4*4+r ----
  int tg0 = tt * TT;
  #pragma unroll
  for (int ni = 0; ni < 6; ++ni) {
    int tw = ni * 16 + l15;
    if (tw < NTW) {
      int t = tw / 22, w = tw - t * 22;
      #pragma unroll
      for (int mi = 0; mi < 2; ++mi) {
        int c0 = wave * 32 + mi * 16 + l4 * 4;
        #pragma unroll
        for (int r = 0; r < 4; ++r) {
          int c = c0 + r;
          out[(size_t)((n * 256 + c) * 512 + tg0 + t) * 22 + w] = acc[mi][ni][r] + B2[c * 25 + w];
        }
      }
    }
  }
}

extern "C" void kernel_launch(void* const* d_in, const int* in_sizes, int n_in,
                              void* d_out, int out_size, void* d_ws, size_t ws_size,
                              hipStream_t stream) {
  (void)in_sizes; (void)n_in; (void)out_size;
  const float* x    = (const float*)d_in[0];
  const float* Ag   = (const float*)d_in[1];
  const float* attA = (const float*)d_in[2];
  const float* W    = (const float*)d_in[3];
  const float* b    = (const float*)d_in[4];
  float* out = (float*)d_out;
  dim3 grid(1024);         // flat = n + 8*tt  (XCD == n)
  bool use_wb = (d_ws != nullptr) && (ws_size >= (size_t)WB_BYTES);
  if (use_wb) {
    unsigned short* Wb = (unsigned short*)d_ws;
    wconv<<<224, 256, 0, stream>>>(W, Wb);
    sgc_fused<true><<<grid, 512, 0, stream>>>(x, Ag, attA, W, Wb, b, out);
  } else {
    sgc_fused<false><<<grid, 512, 0, stream>>>(x, Ag, attA, W, nullptr, b, out);
  }
}

// Round 5
// 278.495 us; speedup vs baseline: 1.5479x; 1.0015x over previous
//
#include <hip/hip_runtime.h>

// S_GC_att_A round 9: R8 (175us, best) + Zs double-buffer -> ONE barrier per k.
// R8 post-mortem: MFMA 44.5us (as predicted), VALU ~43us, HBM 24us-equivalent;
// remaining ~90us = 61 full-drain barriers x 8-wave lockstep. R5 already showed
// dbuf-Zs is functionally correct; it failed there from REGISTER payment (spill).
// R9 pays with LDS instead: +12288B -> 49824B total; 2 blocks x 49.8KB = 99.6KB
// < 160KB/CU so the reg-capped 2-blocks/CU occupancy is untouched.
// Hazards audited: z(k+1) writes buffer p^1 while laggard main(k) reads p; z(k+2)
// reuses p only after barrier(k+1) which post-dates all mains(k); staging touches
// only Xs which main never reads. Single change vs R8 -- clean attribution.
// Tripwires: VGPR>64 => spill; Occupancy<35% => residency loss.

#define TT    4
#define NTW   88     // TT*22
#define XSTR  104    // Xs row stride in bf16 (4*24 + 8 pad)
#define MROWS 176    // 7*24 + 8 pad rows
#define CHUNK 64
#define WB_BYTES (7 * 256 * 256 * 2)

typedef __attribute__((ext_vector_type(8))) __bf16    bf16x8;
typedef __attribute__((ext_vector_type(4))) float     f32x4;
typedef __attribute__((ext_vector_type(8))) short     s16x8;
typedef __attribute__((ext_vector_type(2))) unsigned  u32x2;
typedef __attribute__((ext_vector_type(4))) unsigned  u32x4;

__device__ __forceinline__ unsigned short f2bf_rn(float f) {  // RNE
  union { float f; unsigned u; } x; x.f = f;
  return (unsigned short)((x.u + 0x7FFFu + ((x.u >> 16) & 1u)) >> 16);
}
__device__ __forceinline__ unsigned pk_rh(float a, float b) { // lo=bf(a), hi=bf(b), half-up
  unsigned ua = __builtin_bit_cast(unsigned, a) + 0x8000u;
  unsigned ub = __builtin_bit_cast(unsigned, b) + 0x8000u;
  return __builtin_amdgcn_perm(ub, ua, 0x07060302);           // one v_perm_b32
}

// ---- W fp32 -> bf16 (RNE) into workspace; 224*256*8 = 458752 elems exact
__global__ void wconv(const float* __restrict__ W, unsigned short* __restrict__ Wb) {
  int i = (blockIdx.x * 256 + threadIdx.x) * 8;
  float4 a = *(const float4*)(W + i);
  float4 c = *(const float4*)(W + i + 4);
  s16x8 r;
  r[0] = (short)f2bf_rn(a.x); r[1] = (short)f2bf_rn(a.y);
  r[2] = (short)f2bf_rn(a.z); r[3] = (short)f2bf_rn(a.w);
  r[4] = (short)f2bf_rn(c.x); r[5] = (short)f2bf_rn(c.y);
  r[6] = (short)f2bf_rn(c.z); r[7] = (short)f2bf_rn(c.w);
  *(s16x8*)(Wb + i) = r;
}

__device__ __forceinline__ bf16x8 ldw_f32(const float* p) {   // fallback path
  float4 a = *(const float4*)(p);
  float4 c = *(const float4*)(p + 4);
  u32x4 q;
  q[0] = pk_rh(a.x, a.y); q[1] = pk_rh(a.z, a.w);
  q[2] = pk_rh(c.x, c.y); q[3] = pk_rh(c.z, c.w);
  return __builtin_bit_cast(bf16x8, q);
}

template <bool USE_WB>
__global__ __launch_bounds__(512, 4)
void sgc_fused(const float* __restrict__ x, const float* __restrict__ Ag,
               const float* __restrict__ attA, const float* __restrict__ W,
               const unsigned short* __restrict__ Wb, const float* __restrict__ b,
               float* __restrict__ out) {
  const int bx   = blockIdx.x;
  const int n    = bx & 7;            // XCD == n (x-tile L2 sharing across tt)
  const int tt   = bx >> 3;           // 0..127  (t-tile of 4)
  const int tid  = threadIdx.x;
  const int wave = tid >> 6;          // 0..7
  const int lane = tid & 63;
  const int l15  = lane & 15;
  const int l4   = lane >> 4;
  const int g    = wave & 3;          // z-phase ci-group
  const int h    = wave >> 2;         // z-phase t-half

  // LDS: Xs [64][104] bf16 @0 (13312) | Zs0 [96][64] swz @13312 (12288)
  //      Zs1 @25600 (12288) | Ms [176][32] bf16 @37888 (11264) | Ss @49152 (672)
  //      total 49824 B; 2 blocks/CU -> 99.6KB < 160KB
  __shared__ __align__(16) char smem[49824];
  unsigned short* Xs  = (unsigned short*)(smem);
  unsigned short* Zs0 = (unsigned short*)(smem + 13312);
  unsigned short* Zs1 = (unsigned short*)(smem + 25600);
  unsigned short* Ms  = (unsigned short*)(smem + 37888);
  float*          Ss  = (float*)(smem + 49152);
  float*          B2  = (float*)(smem);          // epilogue reuse: [256][25] f32 = 25600 B
                                                 // (covers Xs+Zs0; last main reads Zs1 - disjoint)

  f32x4 acc[2][6];                               // 48 AGPRs
  #pragma unroll
  for (int i = 0; i < 2; ++i)
    #pragma unroll
    for (int j = 0; j < 6; ++j)
      acc[i][j] = (f32x4){0.f, 0.f, 0.f, 0.f};

  // ---- block init: M~[k][w][v] = M_k[v][w] bf16, zero-padded ----
  for (int i = tid; i < MROWS * 32; i += 512) {
    int row = i >> 5, v = i & 31;
    int k = row / 24, w = row - k * 24;
    float val = 0.f;
    if (row < 168 && w < 22 && v < 22)
      val = (k < 3) ? Ag[(k * 22 + v) * 22 + w]
                    : attA[(((n << 2) + (k - 3)) * 22 + v) * 22 + w];
    Ms[i] = f2bf_rn(val);
  }
  if (tid < 168) {                               // S[k][w] = sum_v M_k[v][w] (fp32 exact)
    int k = tid / 24, w = tid - k * 24;
    float s = 0.f;
    if (w < 22)
      for (int v = 0; v < 22; ++v)
        s += (k < 3) ? Ag[(k * 22 + v) * 22 + w]
                     : attA[(((n << 2) + (k - 3)) * 22 + v) * 22 + w];
    Ss[tid] = s;
  }
  Zs0[88 * CHUNK + tid] = 0;                     // pad rows 88..95, both buffers
  Zs1[88 * CHUNK + tid] = 0;
  for (int i = tid; i < 64 * XSTR / 2; i += 512) ((unsigned*)Xs)[i] = 0; // pads 0, not NaN
  __syncthreads();

  const int ci0 = g * 16 + l4 * 4;               // z-output row this thread owns
  const int cb  = ci0 >> 3, sub = ci0 & 7;
  int p = 0;                                     // Zs parity

  for (int chunk = 0; chunk < 4; ++chunk) {
    // ---- stage x[n, chunk*64..+64, tt*4..+4, :] -> Xs bf16 [ci][t*24+v] ----
    // paired u32 writes: tv pairs at even offsets never straddle a t-row (22 even).
    for (int i = tid; i < CHUNK * 22; i += 512) {
      int ci = i / 22, q = i - ci * 22;
      const float4 f4 = *(const float4*)(x + (size_t)((n * 256 + chunk * CHUNK + ci) * 11264)
                                           + tt * NTW + q * 4);
      int tv0 = q * 4;
      int t0 = tv0 / 22, v0 = tv0 - t0 * 22;
      ((unsigned*)Xs)[ci * 52 + t0 * 12 + (v0 >> 1)] = pk_rh(f4.x, f4.y);
      int tv2 = tv0 + 2;
      int t2 = tv2 / 22, v2 = tv2 - t2 * 22;
      ((unsigned*)Xs)[ci * 52 + t2 * 12 + (v2 >> 1)] = pk_rh(f4.z, f4.w);
    }
    __syncthreads();

    for (int k = 0; k < 7; ++k) {
      unsigned short* Zw = p ? Zs1 : Zs0;

      // ---- W-frag prefetch (global; drained by the barrier, consumed in main) ----
      bf16x8 wf[2][2];
      #pragma unroll
      for (int s = 0; s < 2; ++s)
        #pragma unroll
        for (int mi = 0; mi < 2; ++mi) {
          int c = wave * 32 + mi * 16 + l15;
          size_t idx = (size_t)((k * 256 + c) * 256) + chunk * CHUNK + s * 32 + l4 * 8;
          wf[s][mi] = USE_WB ? *(const bf16x8*)(Wb + idx) : ldw_f32(W + idx);
        }

      // ---- z phase: z[ci,w] = X[ci,v] @ M_k[v,w]; wave (g,h): rows [g*16,+16),
      //      t in {2h, 2h+1}. 8 waves cover all 64 ci x 4 t exactly once. ----
      bf16x8 bm0 = *(const bf16x8*)(&Ms[(k * 24 + l15) * 32 + l4 * 8]);
      bf16x8 bm1 = *(const bf16x8*)(&Ms[(k * 24 + 16 + l15) * 32 + l4 * 8]);
      f32x4 zt[2][2];
      #pragma unroll
      for (int t2 = 0; t2 < 2; ++t2) {
        int t = h * 2 + t2;
        bf16x8 ax = *(const bf16x8*)(&Xs[(g * 16 + l15) * XSTR + t * 24 + l4 * 8]);
        zt[t2][0] = __builtin_amdgcn_mfma_f32_16x16x32_bf16(ax, bm0, (f32x4){0.f,0.f,0.f,0.f}, 0, 0, 0);
        zt[t2][1] = __builtin_amdgcn_mfma_f32_16x16x32_bf16(ax, bm1, (f32x4){0.f,0.f,0.f,0.f}, 0, 0, 0);
      }
      #pragma unroll
      for (int t2 = 0; t2 < 2; ++t2) {
        int t = h * 2 + t2;
        #pragma unroll
        for (int ni = 0; ni < 2; ++ni) {
          int w = ni * 16 + l15;
          if (w < 22) {
            int tw = t * 22 + w;
            int eo = tw * CHUNK + ((cb ^ (tw & 7)) << 3) + sub;
            f32x4 z = zt[t2][ni];
            u32x2 pq; pq[0] = pk_rh(z[0], z[1]); pq[1] = pk_rh(z[2], z[3]);
            *(u32x2*)(&Zw[eo]) = pq;             // 8 B aligned, ~2-way banks
          }
        }
      }
      __syncthreads();                           // the ONLY barrier per k

      // ---- main GEMM: out[c,tw] += Wk[c, ci-chunk] @ z; wave owns c [wave*32,+32) ----
      #pragma unroll
      for (int s = 0; s < 2; ++s) {
        int cb2 = (s << 2) + l4;
        #pragma unroll
        for (int ni = 0; ni < 6; ++ni) {
          int tw = ni * 16 + l15;
          bf16x8 zf = *(const bf16x8*)(&Zw[tw * CHUNK + ((cb2 ^ (tw & 7)) << 3)]);
          #pragma unroll
          for (int mi = 0; mi < 2; ++mi)
            acc[mi][ni] = __builtin_amdgcn_mfma_f32_16x16x32_bf16(wf[s][mi], zf, acc[mi][ni], 0, 0, 0);
        }
      }
      p ^= 1;                                    // next z writes the other buffer
    }
  }
  __syncthreads();                               // all mains done before B2 overwrites

  // ---- bias2[c][w] = sum_k b[k*256+c] * S_k[w]  (Xs+Zs0 dead -> reuse) ----
  for (int i = tid; i < 256 * 22; i += 512) {
    int cl = i / 22, w = i - cl * 22;
    float s = 0.f;
    #pragma unroll
    for (int k = 0; k < 7; ++k) s += b[k * 256 + cl] * Ss[k * 24 + w];
    B2[cl * 25 + w] = s;
  }
  __syncthreads();

  // ---- epilogue: bias + store. C-layout: col=tw, row=l4*4+r ----
  int tg0 = tt * TT;
  #pragma unroll
  for (int ni = 0; ni < 6; ++ni) {
    int tw = ni * 16 + l15;
    if (tw < NTW) {
      int t = tw / 22, w = tw - t * 22;
      #pragma unroll
      for (int mi = 0; mi < 2; ++mi) {
        int c0 = wave * 32 + mi * 16 + l4 * 4;
        #pragma unroll
        for (int r = 0; r < 4; ++r) {
          int c = c0 + r;
          out[(size_t)((n * 256 + c) * 512 + tg0 + t) * 22 + w] = acc[mi][ni][r] + B2[c * 25 + w];
        }
      }
    }
  }
}

extern "C" void kernel_launch(void* const* d_in, const int* in_sizes, int n_in,
                              void* d_out, int out_size, void* d_ws, size_t ws_size,
                              hipStream_t stream) {
  (void)in_sizes; (void)n_in; (void)out_size;
  const float* x    = (const float*)d_in[0];
  const float* Ag   = (const float*)d_in[1];
  const float* attA = (const float*)d_in[2];
  const float* W    = (const float*)d_in[3];
  const float* b    = (const float*)d_in[4];
  float* out = (float*)d_out;
  dim3 grid(1024);         // flat = n + 8*tt  (XCD == n)
  bool use_wb = (d_ws != nullptr) && (ws_size >= (size_t)WB_BYTES);
  if (use_wb) {
    unsigned short* Wb = (unsigned short*)d_ws;
    wconv<<<224, 256, 0, stream>>>(W, Wb);
    sgc_fused<true><<<grid, 512, 0, stream>>>(x, Ag, attA, W, Wb, b, out);
  } else {
    sgc_fused<false><<<grid, 512, 0, stream>>>(x, Ag, attA, W, nullptr, b, out);
  }
}